// Round 1
// baseline (461.507 us; speedup 1.0000x reference)
//
#include <hip/hip_runtime.h>
#include <hip/hip_bf16.h>
#include <math.h>

#define BE   256
#define DIM  256
#define OUTD 128
#define LCL  256
#define LEV  512
#define NEGV -1e18f

typedef short  bf16x8  __attribute__((ext_vector_type(8)));
typedef float  floatx4 __attribute__((ext_vector_type(4)));

union BF1 { __hip_bfloat16 h; unsigned short u; };
union BF2 { __hip_bfloat162 h; unsigned int u; };

__device__ __forceinline__ float fast_tanh(float x) {
    float xc = fminf(fmaxf(x, -15.f), 15.f);
    float e = __expf(2.f * xc);                       // e^{2x}
    return (e - 1.f) * __builtin_amdgcn_rcpf(e + 1.f);
}

// ---------------------------------------------------------------------------
// K1: stage-A mean partials (float4-vectorized) + W-transpose fold.
// blocks [0,3072): pair=b/12, chunk=b%12; chunk<4 -> claim 64-row chunk,
// else evidence 64-row chunk. Writes partial[b][256].
// blocks [3072,3328): convert+transpose W[:D] -> bf16 W^T.
// ---------------------------------------------------------------------------
__global__ __launch_bounds__(256) void k_meanprep(
    const float* __restrict__ claim, const float* __restrict__ evidence,
    const float* __restrict__ W1, const float* __restrict__ W2,
    float* __restrict__ partial,
    unsigned short* __restrict__ WT1, unsigned short* __restrict__ WT2)
{
    const int b = blockIdx.x;
    const int t = threadIdx.x;
    if (b >= 3072) {
        const int idx = b - 3072;          // 0..255
        const int side = idx >> 7;
        const int n = idx & 127;
        const float* W = side ? W2 : W1;
        unsigned short* WT = side ? WT2 : WT1;
        BF1 c; c.h = __float2bfloat16(W[(size_t)t * OUTD + n]);
        WT[n * DIM + t] = c.u;
        return;
    }
    const int pair = b / 12;
    const int chunk = b % 12;
    const float4* src4 = (const float4*)((chunk < 4)
        ? claim + ((size_t)pair * LCL + chunk * 64) * DIM
        : evidence + ((size_t)pair * LEV + (chunk - 4) * 64) * DIM);
    const int col4 = t & 63;       // which float4 of the 256-dim row
    const int rgrp = t >> 6;       // 4 row groups of 16 rows
    float4 a = make_float4(0.f, 0.f, 0.f, 0.f);
#pragma unroll
    for (int r = 0; r < 16; ++r) {
        const float4 v = src4[(rgrp * 16 + r) * 64 + col4];
        a.x += v.x; a.y += v.y; a.z += v.z; a.w += v.w;
    }
    __shared__ float4 sm4[4][64];
    sm4[rgrp][col4] = a;
    __syncthreads();
    if (t < 64) {
        const float4 s0 = sm4[0][t], s1 = sm4[1][t], s2 = sm4[2][t], s3 = sm4[3][t];
        ((float4*)(partial + (size_t)b * DIM))[t] =
            make_float4(s0.x + s1.x + s2.x + s3.x,
                        s0.y + s1.y + s2.y + s3.y,
                        s0.z + s1.z + s2.z + s3.z,
                        s0.w + s1.w + s2.w + s3.w);
    }
}

// ---------------------------------------------------------------------------
// K2: reduce partials -> means, then bias GEMMs. 512 threads:
// side = t>>8 (0: claim-mean @ W1[D:] -> bias_e, 1: evid-mean @ W2[D:] -> bias_c)
// o = t&127, dh = (t>>7)&1 splits the D-loop in half; LDS combine.
// ---------------------------------------------------------------------------
__global__ __launch_bounds__(512) void k_redbias(
    const float* __restrict__ partial,
    const float* __restrict__ W1, const float* __restrict__ W2,
    float* __restrict__ bias_e, float* __restrict__ bias_c)
{
    const int pair = blockIdx.x;
    const int t = threadIdx.x;
    __shared__ float sm[2][DIM];
    __shared__ float sb[2][2][OUTD];
    if (t < 256) {
        float s = 0.f;
#pragma unroll
        for (int j = 0; j < 4; ++j) s += partial[((size_t)pair * 12 + j) * DIM + t];
        sm[0][t] = s * (1.f / LCL);
    } else {
        const int t2 = t - 256;
        float s = 0.f;
#pragma unroll
        for (int j = 4; j < 12; ++j) s += partial[((size_t)pair * 12 + j) * DIM + t2];
        sm[1][t2] = s * (1.f / LEV);
    }
    __syncthreads();
    const int side = t >> 8, o = t & 127, dh = (t >> 7) & 1;
    const float* W = side ? W2 : W1;
    const float* m = sm[side];
    float s = 0.f;
#pragma unroll 8
    for (int i = 0; i < 128; ++i) {
        const int d = dh * 128 + i;
        s += m[d] * W[(size_t)(DIM + d) * OUTD + o];
    }
    sb[side][dh][o] = s;
    __syncthreads();
    if (t < 256) {
        const int sd = t >> 7, oo = t & 127;
        const float bv = sb[sd][0][oo] + sb[sd][1][oo];
        (sd ? bias_c : bias_e)[pair * OUTD + oo] = bv;
    }
}

// ---------------------------------------------------------------------------
// K3: fused scores + online-softmax + weighted sum. One block per (pair,side).
// bid<256: evidence (L=512); bid>=256: claim (L=256). 512 thr = 8 waves.
// Per 128-row tile: stage fp32->bf16 LDS (full K=256), MFMA scores
// (8 waves x [32 rows x 64 cols], identical fragment mapping to the verified
// 4-wave version), tanh-dot epilogue, mask, online softmax (running m,l,O),
// then fp32 weighted-sum re-reading the just-staged tile (L1/L2-hot).
// ---------------------------------------------------------------------------
__global__ __launch_bounds__(512, 4) void k_fused(
    const float* __restrict__ claim, const float* __restrict__ evidence,
    const unsigned short* __restrict__ WT1, const unsigned short* __restrict__ WT2,
    const float* __restrict__ w2v, const float* __restrict__ w1v,
    const float* __restrict__ bias_e, const float* __restrict__ bias_c,
    const int* __restrict__ emask, const int* __restrict__ cmask,
    float* __restrict__ out)
{
    constexpr int SAPC = 264;                  // 256 + 8 pad, shorts (4-bank row shift)
    __shared__ unsigned short sA[128 * SAPC];  // 67584 B
    __shared__ float sred[128][2];
    __shared__ float patt[128];
    __shared__ float rmax[2], rsum[2];
    __shared__ float ofin[256];

    const int bid = blockIdx.x;
    const bool is_ev = bid < BE;
    const int pair = bid & (BE - 1);
    const float* __restrict__ seq  = is_ev ? evidence : claim;
    const unsigned short* __restrict__ WT = is_ev ? WT1 : WT2;
    const float* __restrict__ wvec = is_ev ? w2v : w1v;
    const float* __restrict__ bias = is_ev ? bias_e : bias_c;
    const int*   __restrict__ mask = is_ev ? emask : cmask;
    float* __restrict__ outp       = is_ev ? out + (size_t)BE * DIM : out;
    const int L  = is_ev ? LEV : LCL;
    const int NT = L >> 7;                     // 128-row tiles

    const int t = threadIdx.x;
    const int lane = t & 63;
    const int wv = t >> 6;                     // 0..7
    const int wrow = wv >> 1;                  // 0..3 -> 32-row slice
    const int wcolg = wv & 1;                  // 0..1 -> 64-col half
    const int q = lane >> 4, c16 = lane & 15;
    const int d = t & 255, rg = t >> 8;        // wsum mapping

    float bc[4], wc[4];
#pragma unroll
    for (int ct = 0; ct < 4; ++ct) {
        const int col = wcolg * 64 + ct * 16 + c16;
        bc[ct] = bias[pair * OUTD + col];
        wc[ct] = wvec[col];
    }
    const unsigned short* wbase = WT + (size_t)(wcolg * 64 + c16) * DIM + q * 8;

    float Oacc = 0.f;
    float m_run = -INFINITY, l_run = 0.f;

    for (int tile = 0; tile < NT; ++tile) {
        // ---- stage 128x256 fp32 -> bf16 LDS ----
        const float4* sp4 = (const float4*)(seq + ((size_t)pair * L + tile * 128) * DIM);
#pragma unroll 8
        for (int i = 0; i < 16; ++i) {
            const int idx = t + i * 512;
            const float4 v = sp4[idx];
            const int row = idx >> 6, f4 = idx & 63;
            BF2 lo, hi;
            lo.h = __float22bfloat162_rn(make_float2(v.x, v.y));
            hi.h = __float22bfloat162_rn(make_float2(v.z, v.w));
            *(uint2*)&sA[row * SAPC + f4 * 4] = make_uint2(lo.u, hi.u);
        }
        __syncthreads();

        // ---- MFMA scores: 8 waves x (2 row-frags x 4 col-frags) ----
        floatx4 acc[2][4];
#pragma unroll
        for (int ra = 0; ra < 2; ++ra)
#pragma unroll
            for (int ct = 0; ct < 4; ++ct) acc[ra][ct] = (floatx4){0.f, 0.f, 0.f, 0.f};
        bf16x8 bcur[4], bnxt[4];
#pragma unroll
        for (int ct = 0; ct < 4; ++ct)
            bcur[ct] = *(const bf16x8*)(wbase + (size_t)ct * 16 * DIM);
#pragma unroll
        for (int ks = 0; ks < 8; ++ks) {
            if (ks < 7) {
#pragma unroll
                for (int ct = 0; ct < 4; ++ct)
                    bnxt[ct] = *(const bf16x8*)(wbase + (size_t)ct * 16 * DIM + (ks + 1) * 32);
            }
            bf16x8 af[2];
#pragma unroll
            for (int ra = 0; ra < 2; ++ra)
                af[ra] = *(const bf16x8*)&sA[(wrow * 32 + ra * 16 + c16) * SAPC + ks * 32 + q * 8];
#pragma unroll
            for (int ra = 0; ra < 2; ++ra)
#pragma unroll
                for (int ct = 0; ct < 4; ++ct)
                    acc[ra][ct] = __builtin_amdgcn_mfma_f32_16x16x32_bf16(af[ra], bcur[ct], acc[ra][ct], 0, 0, 0);
#pragma unroll
            for (int ct = 0; ct < 4; ++ct) bcur[ct] = bnxt[ct];
        }

        // ---- tanh-dot epilogue -> per-row score halves in sred ----
#pragma unroll
        for (int ra = 0; ra < 2; ++ra) {
#pragma unroll
            for (int reg = 0; reg < 4; ++reg) {
                float s = 0.f;
#pragma unroll
                for (int ct = 0; ct < 4; ++ct)
                    s += fast_tanh(acc[ra][ct][reg] + bc[ct]) * wc[ct];
#pragma unroll
                for (int off = 1; off < 16; off <<= 1) s += __shfl_xor(s, off, 64);
                if (c16 == 0)
                    sred[wrow * 32 + ra * 16 + q * 4 + reg][wcolg] = s;
            }
        }
        __syncthreads();

        // ---- mask + tile max (waves 0,1) ----
        if (t < 128) {
            float a = sred[t][0] + sred[t][1];
            a = mask[pair * L + tile * 128 + t] ? a : NEGV;
            patt[t] = a;
            float mx = a;
#pragma unroll
            for (int off = 1; off < 64; off <<= 1) mx = fmaxf(mx, __shfl_xor(mx, off, 64));
            if (lane == 0) rmax[wv] = mx;
        }
        __syncthreads();
        const float newm = fmaxf(m_run, fmaxf(rmax[0], rmax[1]));
        const float scale = expf(m_run - newm);   // first tile: expf(-inf)=0
        if (t < 128) {
            const float e = expf(patt[t] - newm);
            patt[t] = e;
            float sm = e;
#pragma unroll
            for (int off = 1; off < 64; off <<= 1) sm += __shfl_xor(sm, off, 64);
            if (lane == 0) rsum[wv] = sm;
        }
        __syncthreads();
        l_run = l_run * scale + rsum[0] + rsum[1];
        m_run = newm;
        Oacc *= scale;

        // ---- weighted-sum accumulate; tile rows are L1/L2-hot fp32 ----
        const float* sp = seq + ((size_t)pair * L + tile * 128 + rg * 64) * DIM + d;
#pragma unroll 8
        for (int r = 0; r < 64; ++r)
            Oacc += patt[rg * 64 + r] * sp[(size_t)r * DIM];
        // no barrier needed: next write to patt is 2 barriers downstream
    }

    // ---- combine the two row-group halves, normalize, store ----
    if (rg == 0) ofin[d] = Oacc;
    __syncthreads();
    if (rg == 1) ofin[d] += Oacc;
    __syncthreads();
    if (t < 256)
        outp[(size_t)pair * DIM + t] = ofin[t] / l_run;
}

// ---------------------------------------------------------------------------
extern "C" void kernel_launch(void* const* d_in, const int* in_sizes, int n_in,
                              void* d_out, int out_size, void* d_ws, size_t ws_size,
                              hipStream_t stream) {
    const float* claim    = (const float*)d_in[0];
    const int*   cmask    = (const int*)  d_in[1];
    const float* evidence = (const float*)d_in[2];
    const int*   emask    = (const int*)  d_in[3];
    const float* W1       = (const float*)d_in[4];
    const float* w2       = (const float*)d_in[5];
    const float* W2       = (const float*)d_in[6];
    const float* w1       = (const float*)d_in[7];
    float* out = (float*)d_out;

    float* ws = (float*)d_ws;
    float* partial = ws;                         // 3072*256 floats
    float* bias_e  = partial + 3072 * DIM;       // 256*128
    float* bias_c  = bias_e + BE * OUTD;         // 256*128
    unsigned short* WT1 = (unsigned short*)(bias_c + BE * OUTD);
    unsigned short* WT2 = WT1 + OUTD * DIM;

    k_meanprep<<<3328, 256, 0, stream>>>(claim, evidence, W1, W2, partial, WT1, WT2);
    k_redbias<<<BE, 512, 0, stream>>>(partial, W1, W2, bias_e, bias_c);
    // output order: c_hat first (claim side), e_hat second (evidence side)
    k_fused<<<512, 512, 0, stream>>>(claim, evidence, WT1, WT2, w2, w1,
                                     bias_e, bias_c, emask, cmask, out);
}